// Round 11
// baseline (181.501 us; speedup 1.0000x reference)
//
#include <hip/hip_runtime.h>
#include <hip/hip_bf16.h>

typedef __attribute__((ext_vector_type(4))) float   f32x4;
typedef __attribute__((ext_vector_type(8))) __bf16  bf16x8;
typedef __attribute__((ext_vector_type(4))) __bf16  bf16x4;

#define NB 4
#define SS 2048
#define DD 1024

__device__ __forceinline__ void gload_lds16(const void* g, void* l) {
  __builtin_amdgcn_global_load_lds((const __attribute__((address_space(1))) void*)g,
                                   (__attribute__((address_space(3))) void*)l,
                                   16, 0, 0);
}

// fp32 -> bf16 convert for the three [4,2048,1024] inputs. grid (8192,1,3) x 256
__global__ __launch_bounds__(256) void cvt_in_kernel(
    const float* __restrict__ q, const float* __restrict__ k,
    const float* __restrict__ v, __bf16* __restrict__ X)
{
  const float* src = blockIdx.z == 0 ? q : (blockIdx.z == 1 ? k : v);
  __bf16* dst = X + (size_t)blockIdx.z * (size_t)(NB * SS * DD);
  size_t i = ((size_t)blockIdx.x * 256 + threadIdx.x) * 4;
  float4 f = *(const float4*)&src[i];
  bf16x4 o = { (__bf16)f.x, (__bf16)f.y, (__bf16)f.z, (__bf16)f.w };
  *(bf16x4*)&dst[i] = o;
}

// W[k][n] fp32 -> Wt[n][k] bf16 (transpose+convert); also copy biases. grid (32,32,3) x 256
__global__ __launch_bounds__(256) void prep_w_kernel(
    const float* __restrict__ wq, const float* __restrict__ wk, const float* __restrict__ wv,
    const float* __restrict__ bq, const float* __restrict__ bk, const float* __restrict__ bv,
    __bf16* __restrict__ Wt, float* __restrict__ biasbuf)
{
  const int z = blockIdx.z;
  const float* W  = z == 0 ? wq : (z == 1 ? wk : wv);
  const float* bi = z == 0 ? bq : (z == 1 ? bk : bv);
  __bf16* dst = Wt + (size_t)z * (size_t)(DD * DD);
  const int n0 = blockIdx.x * 32, k0 = blockIdx.y * 32;
  __shared__ float t[32][33];
  const int tx = threadIdx.x & 31, ty = threadIdx.x >> 5;
  #pragma unroll
  for (int i = 0; i < 4; i++)
    t[ty + 8 * i][tx] = W[(size_t)(k0 + ty + 8 * i) * DD + n0 + tx];
  __syncthreads();
  #pragma unroll
  for (int i = 0; i < 4; i++)
    dst[(size_t)(n0 + ty + 8 * i) * DD + k0 + tx] = (__bf16)t[tx][ty + 8 * i];
  if (blockIdx.x == 0 && blockIdx.y == 0) {
    #pragma unroll
    for (int i = 0; i < 4; i++)
      biasbuf[z * DD + threadIdx.x + 256 * i] = bi[threadIdx.x + 256 * i];
  }
}

// ---------------------------------------------------------------------------
// gemm3 (projections): 256x256 tile, BK=32, 8 waves (2M x 4N, wave 128x64),
// dbuf 64 KiB LDS -> 2 blocks/CU, grid 384 = all-resident (0.75 rounds).
// Paired-row LDS image: phys row r (128 B) = M-rows {2r, 2r+1} (64 B each),
// XOR-swizzle on the FULL in-row byte: phys = c ^ ((r&7)<<4), c = h*64+k*2.
// Per K-step: {12 ds_read; lgkm0; barrier; STAGE(t+2); 32 MFMA; vmcnt(4); barrier}
// z==2 writes V transposed: Vt[b][d][s].
// ---------------------------------------------------------------------------

#define G3A(BUF) ((BUF) * 16384)
#define G3B(BUF) (32768 + (BUF) * 16384)

#define G3_STAGE(BUF, T) do { int t_ = (T); if (t_ >= 32) t_ = 0;               \
  const __bf16* gA_ = Ablk + (size_t)t_ * 32;                                   \
  const __bf16* gB_ = Bblk + (size_t)t_ * 32;                                   \
  gload_lds16(gA_ + so0, smem + G3A(BUF) + tid * 16);                           \
  gload_lds16(gA_ + so1, smem + G3A(BUF) + 8192 + tid * 16);                    \
  gload_lds16(gB_ + so0, smem + G3B(BUF) + tid * 16);                           \
  gload_lds16(gB_ + so1, smem + G3B(BUF) + 8192 + tid * 16); } while (0)

__global__ __launch_bounds__(512, 2) void gemm3_kernel(
    const __bf16* __restrict__ X, const __bf16* __restrict__ Wt,
    const float* __restrict__ bias,
    __bf16* __restrict__ Qo, __bf16* __restrict__ Ko, __bf16* __restrict__ Vt)
{
  extern __shared__ char smem[];

  const int gx = gridDim.x, gy = gridDim.y;
  const int nwg = gx * gy * gridDim.z;
  int lin = blockIdx.x + gx * (blockIdx.y + gy * blockIdx.z);
  const int cpx = nwg >> 3;
  int swz = (lin & 7) * cpx + (lin >> 3);
  const int bx = swz % gx;
  int rem = swz / gx;
  const int by = rem % gy;
  const int bz = rem / gy;

  const long brow = (long)by * 256, bcol = (long)bx * 256;
  const __bf16* Ablk = X + (size_t)bz * 8388608 + (size_t)brow * 1024;
  const __bf16* Bblk = Wt + (size_t)bz * 1048576 + (size_t)bcol * 1024;

  const int tid  = threadIdx.x;
  const int lane = tid & 63;
  const int wid  = tid >> 6;
  const int wm = wid >> 2, wn = wid & 3;      // 2M x 4N
  const int l15 = lane & 15, l4 = lane >> 4;

  // STAGE source offsets (inverse of paired-row swizzled image), 2 issues
  int so0, so1;
  #pragma unroll
  for (int i = 0; i < 2; ++i) {
    const int p = i * 8192 + tid * 16;
    const int r = p >> 7;                      // phys row 0..127
    const int c = (p & 127) ^ ((r & 7) << 4);  // unswizzled byte-in-row
    const int R = 2 * r + (c >> 6);            // logical row 0..255
    const int kb = c & 63;                     // k-bytes 0..63
    const int off = R * 1024 + (kb >> 1);
    if (i == 0) so0 = off; else so1 = off;
  }

  // fragment read bases (bytes). lane reads M-row R = wbase + mi*16 + l15,
  // k-elems l4*8..+8. phys r = R>>1; phys byte = ((R&1)*64 + l4*16) ^ ((r&7)<<4).
  const int rs = l15 >> 1;                    // phys-row-within-group (= r&7)
  const int fb = (((l15 & 1) * 64) + (l4 * 16)) ^ ((rs & 7) << 4);   // FIXED: XOR over full byte
  const int aBase = (wm * 64 + rs) * 128 + fb;   // wave M-half: 128 rows -> 64 phys
  const int bBase = (wn * 32 + rs) * 128 + fb;   // wave N: 64 rows -> 32 phys

  f32x4 acc[8][4] = {};
  bf16x8 af[8], bfr[4];

  G3_STAGE(0, 0);
  G3_STAGE(1, 1);
  asm volatile("s_waitcnt vmcnt(4)" ::: "memory");   // tile 0 landed
  __builtin_amdgcn_s_barrier();

  for (int t = 0; t < 32; ++t) {
    const int cur = t & 1;
    const int ab = cur * 16384;
    const int bb = 32768 + cur * 16384;
    #pragma unroll
    for (int mi = 0; mi < 8; ++mi)
      af[mi] = *(const bf16x8*)(smem + ab + aBase + mi * 1024);
    #pragma unroll
    for (int ni = 0; ni < 4; ++ni)
      bfr[ni] = *(const bf16x8*)(smem + bb + bBase + ni * 1024);
    asm volatile("s_waitcnt lgkmcnt(0)" ::: "memory");
    __builtin_amdgcn_sched_barrier(0);
    __builtin_amdgcn_s_barrier();                    // all waves done reading cur
    G3_STAGE(cur, t + 2);                            // overwrite cur with t+2
    __builtin_amdgcn_s_setprio(1);
    #pragma unroll
    for (int mi = 0; mi < 8; ++mi)
      #pragma unroll
      for (int ni = 0; ni < 4; ++ni)
        acc[mi][ni] = __builtin_amdgcn_mfma_f32_16x16x32_bf16(
            af[mi], bfr[ni], acc[mi][ni], 0, 0, 0);
    __builtin_amdgcn_s_setprio(0);
    __builtin_amdgcn_sched_barrier(0);
    asm volatile("s_waitcnt vmcnt(4)" ::: "memory"); // tile t+1 landed
    __builtin_amdgcn_s_barrier();                    // publish
  }

  // epilogue
  if (bz == 2) {
    // V transposed: Vt[b][d][s]
    #pragma unroll
    for (int mi = 0; mi < 8; ++mi) {
      #pragma unroll
      for (int ni = 0; ni < 4; ++ni) {
        const long row = brow + wm * 128 + mi * 16 + l4 * 4;
        const long col = bcol + wn * 64 + ni * 16 + l15;
        const float bvv = bias[2 * DD + col];
        const long bb2 = row >> 11, s = row & 2047;
        bf16x4 pk = { (__bf16)(acc[mi][ni][0] + bvv), (__bf16)(acc[mi][ni][1] + bvv),
                      (__bf16)(acc[mi][ni][2] + bvv), (__bf16)(acc[mi][ni][3] + bvv) };
        *(bf16x4*)&Vt[bb2 * 2097152 + col * 2048 + s] = pk;
      }
    }
  } else {
    __bf16* C = bz == 0 ? Qo : Ko;
    #pragma unroll
    for (int mi = 0; mi < 8; ++mi) {
      #pragma unroll
      for (int ni = 0; ni < 4; ++ni) {
        const long row = brow + wm * 128 + mi * 16 + l4 * 4;
        const long col = bcol + wn * 64 + ni * 16 + l15;
        const float bvv = bias[bz * DD + col];
        #pragma unroll
        for (int e = 0; e < 4; ++e)
          C[(row + e) * 1024 + col] = (__bf16)(acc[mi][ni][e] + bvv);
      }
    }
  }
}

// ---------------------------------------------------------------------------
// gemm2b (PV): 128x128 tile, BK=64, 4 waves, dbuf 64 KiB -> 2 blocks/CU.
// out = (P @ Vt^T) / rowsum(P) -> fp32. (unchanged, proven R9)
// ---------------------------------------------------------------------------

#define G2A(BUF) ((BUF) * 16384)
#define G2B(BUF) (32768 + (BUF) * 16384)

#define G2_STAGE(BUF, T) do { int t_ = (T); if (t_ >= NT) t_ = 0;               \
  const __bf16* gA_ = Ablk + (size_t)t_ * 64;                                   \
  const __bf16* gB_ = Bblk + (size_t)t_ * 64;                                   \
  gload_lds16(gA_ + o0, smem + G2A(BUF) + tid * 16);                            \
  gload_lds16(gA_ + o1, smem + G2A(BUF) + 4096 + tid * 16);                     \
  gload_lds16(gA_ + o2, smem + G2A(BUF) + 8192 + tid * 16);                     \
  gload_lds16(gA_ + o3, smem + G2A(BUF) + 12288 + tid * 16);                    \
  gload_lds16(gB_ + o0, smem + G2B(BUF) + tid * 16);                            \
  gload_lds16(gB_ + o1, smem + G2B(BUF) + 4096 + tid * 16);                     \
  gload_lds16(gB_ + o2, smem + G2B(BUF) + 8192 + tid * 16);                     \
  gload_lds16(gB_ + o3, smem + G2B(BUF) + 12288 + tid * 16); } while (0)

__global__ __launch_bounds__(256, 2) void gemm2b_kernel(
    const __bf16* __restrict__ A, const __bf16* __restrict__ B,
    float* __restrict__ Fout,
    int K, int lda, int ldb, int ldc,
    long strideA, long strideB, long strideC)
{
  extern __shared__ char smem[];

  const int gx = gridDim.x, gy = gridDim.y;
  const int nwg = gx * gy * gridDim.z;
  int lin = blockIdx.x + gx * (blockIdx.y + gy * blockIdx.z);
  const int cpx = nwg >> 3;
  int swz = (lin & 7) * cpx + (lin >> 3);
  const int bx = swz % gx;
  int rem = swz / gx;
  const int by = rem % gy;
  const int bz = rem / gy;

  const long brow = (long)by * 128, bcol = (long)bx * 128;
  const __bf16* Ablk = A + (size_t)bz * strideA + (size_t)brow * lda;
  const __bf16* Bblk = B + (size_t)bz * strideB + (size_t)bcol * ldb;

  const int tid  = threadIdx.x;
  const int lane = tid & 63;
  const int wid  = tid >> 6;
  const int wm = wid >> 1, wn = wid & 1;
  const int l15 = lane & 15, l4 = lane >> 4;
  const int lx = (lane & 7) << 4;

  const int NT = K >> 6;

  int o0, o1, o2, o3;
  #pragma unroll
  for (int i = 0; i < 4; ++i) {
    const int p = i * 4096 + tid * 16;
    const int r = p >> 7;
    const int kb = (p ^ ((r & 7) << 4)) & 127;
    const int off = r * lda + (kb >> 1);
    if (i == 0) o0 = off; else if (i == 1) o1 = off;
    else if (i == 2) o2 = off; else o3 = off;
  }

  int ara[2], brb[2];
  #pragma unroll
  for (int ks = 0; ks < 2; ++ks) {
    ara[ks] = ((((wm * 64 + l15) * 64 + l4 * 8) * 2) + ks * 64) ^ lx;
    brb[ks] = ((((wn * 64 + l15) * 64 + l4 * 8) * 2) + ks * 64) ^ lx;
  }

  f32x4 acc[4][4] = {};
  f32x4 accs[4] = {};
  bf16x8 af[4][2], bf[4][2];
  bf16x8 onesf;
  #pragma unroll
  for (int j = 0; j < 8; ++j) onesf[j] = (__bf16)1.0f;

  G2_STAGE(0, 0);
  G2_STAGE(1, 1);
  asm volatile("s_waitcnt vmcnt(8)" ::: "memory");
  __builtin_amdgcn_s_barrier();

  for (int t = 0; t < NT; ++t) {
    const int cur = t & 1;
    const int abase = cur * 16384;
    const int bbase = 32768 + cur * 16384;
    #pragma unroll
    for (int mi = 0; mi < 4; ++mi)
      #pragma unroll
      for (int ks = 0; ks < 2; ++ks)
        af[mi][ks] = *(const bf16x8*)(smem + abase + ara[ks] + mi * 2048);
    #pragma unroll
    for (int ni = 0; ni < 4; ++ni)
      #pragma unroll
      for (int ks = 0; ks < 2; ++ks)
        bf[ni][ks] = *(const bf16x8*)(smem + bbase + brb[ks] + ni * 2048);
    asm volatile("s_waitcnt lgkmcnt(0)" ::: "memory");
    __builtin_amdgcn_sched_barrier(0);
    __builtin_amdgcn_s_barrier();
    G2_STAGE(cur, t + 2);
    __builtin_amdgcn_s_setprio(1);
    #pragma unroll
    for (int mi = 0; mi < 4; ++mi)
      #pragma unroll
      for (int ni = 0; ni < 4; ++ni)
        #pragma unroll
        for (int ks = 0; ks < 2; ++ks)
          acc[mi][ni] = __builtin_amdgcn_mfma_f32_16x16x32_bf16(
              af[mi][ks], bf[ni][ks], acc[mi][ni], 0, 0, 0);
    #pragma unroll
    for (int mi = 0; mi < 4; ++mi)
      #pragma unroll
      for (int ks = 0; ks < 2; ++ks)
        accs[mi] = __builtin_amdgcn_mfma_f32_16x16x32_bf16(
            af[mi][ks], onesf, accs[mi], 0, 0, 0);
    __builtin_amdgcn_s_setprio(0);
    __builtin_amdgcn_sched_barrier(0);
    asm volatile("s_waitcnt vmcnt(8)" ::: "memory");
    __builtin_amdgcn_s_barrier();
  }

  float* C = Fout + (size_t)bz * strideC;
  #pragma unroll
  for (int mi = 0; mi < 4; ++mi) {
    f32x4 inv;
    #pragma unroll
    for (int e = 0; e < 4; ++e) inv[e] = 1.0f / accs[mi][e];
    #pragma unroll
    for (int ni = 0; ni < 4; ++ni) {
      const long row = brow + wm * 64 + mi * 16 + l4 * 4;
      const long col = bcol + wn * 64 + ni * 16 + l15;
      #pragma unroll
      for (int e = 0; e < 4; ++e)
        C[(row + e) * (size_t)ldc + col] = acc[mi][ni][e] * inv[e];
    }
  }
}

// ---------------------------------------------------------------------------
// 256x256 8-phase counted-vmcnt GEMM (scores): P = exp(Q @ K^T * scale) -> bf16
// (unchanged, proven)
// ---------------------------------------------------------------------------

#define A_OFF(BUF, MH) (((BUF)*2 + (MH)) * 16384)
#define B_OFF(BUF, NH) (65536 + ((BUF)*2 + (NH)) * 16384)

#define STAGE_A(BUF, MH, T) do { int t_ = (T); if (t_ >= NT) t_ = 0;            \
  const __bf16* gs_ = Ablk + (size_t)(MH) * (64 * (size_t)lda) + (size_t)t_ * 64; \
  gload_lds16(gs_ + aoff0, smem + A_OFF(BUF, MH) + tid * 16);                    \
  gload_lds16(gs_ + aoff1, smem + A_OFF(BUF, MH) + 8192 + tid * 16); } while (0)

#define STAGE_B(BUF, NH, T) do { int t_ = (T); if (t_ >= NT) t_ = 0;            \
  const __bf16* gs_ = Bblk + (size_t)(NH) * (32 * (size_t)ldb) + (size_t)t_ * 64; \
  gload_lds16(gs_ + boff0, smem + B_OFF(BUF, NH) + tid * 16);                    \
  gload_lds16(gs_ + boff1, smem + B_OFF(BUF, NH) + 8192 + tid * 16); } while (0)

#define DSREAD_A(DST, BUF, MH)                                                  \
  _Pragma("unroll") for (int mi = 0; mi < 4; ++mi) {                            \
    _Pragma("unroll") for (int ks = 0; ks < 2; ++ks)                            \
      DST[mi][ks] = *(const bf16x8*)(smem + A_OFF(BUF, MH) + arb[ks] + mi * 2048); }

#define DSREAD_BS(DST, BUF, NH)                                                 \
  _Pragma("unroll") for (int ni = 0; ni < 2; ++ni) {                            \
    _Pragma("unroll") for (int ks = 0; ks < 2; ++ks)                            \
      DST[ni][ks] = *(const bf16x8*)(smem + B_OFF(BUF, NH) + brb[ks] + ni * 2048); }

#define BARRIER_MFMA(AF, BF, MH, NH) do {                                       \
  __builtin_amdgcn_s_barrier();                                                 \
  asm volatile("s_waitcnt lgkmcnt(0)" ::: "memory");                            \
  __builtin_amdgcn_sched_barrier(0);                                            \
  __builtin_amdgcn_s_setprio(1);                                                \
  _Pragma("unroll") for (int mi = 0; mi < 4; ++mi)                              \
  _Pragma("unroll") for (int ni = 0; ni < 2; ++ni)                              \
  _Pragma("unroll") for (int ks = 0; ks < 2; ++ks)                              \
    acc[(MH)*4+mi][(NH)*2+ni] = __builtin_amdgcn_mfma_f32_16x16x32_bf16(        \
        AF[mi][ks], BF[ni][ks], acc[(MH)*4+mi][(NH)*2+ni], 0, 0, 0);            \
  __builtin_amdgcn_s_setprio(0);                                                \
  __builtin_amdgcn_sched_barrier(0);                                            \
  __builtin_amdgcn_s_barrier(); } while (0)

__global__ __launch_bounds__(512) void gemm8p_kernel(
    const __bf16* __restrict__ A, const __bf16* __restrict__ B,
    float scale, void* __restrict__ Cout,
    int K, int lda, int ldb, int ldc,
    long strideA, long strideB, long strideC)
{
  extern __shared__ char smem[];

  const int gx = gridDim.x, gy = gridDim.y;
  const int nwg = gx * gy * gridDim.z;
  int lin = blockIdx.x + gx * (blockIdx.y + gy * blockIdx.z);
  const int cpx = nwg >> 3;
  int swz = (lin & 7) * cpx + (lin >> 3);
  const int bx = swz % gx;
  int rem = swz / gx;
  const int by = rem % gy;
  const int bz = rem / gy;

  const long brow = (long)by * 256, bcol = (long)bx * 256;
  const __bf16* Ablk = A + (size_t)bz * strideA + (size_t)brow * lda;
  const __bf16* Bblk = B + (size_t)bz * strideB + (size_t)bcol * ldb;

  const int tid  = threadIdx.x;
  const int lane = tid & 63;
  const int wid  = tid >> 6;
  const int wm = wid >> 2, wn = wid & 3;
  const int l15 = lane & 15, l4 = lane >> 4;
  const int lx = (lane & 7) << 4;

  const int NT = K >> 6;
  const int niter = NT >> 1;

  int aoff0, aoff1, boff0, boff1;
  #pragma unroll
  for (int i = 0; i < 2; ++i) {
    const int p = i * 8192 + tid * 16;
    const int l = p ^ (((p >> 7) & 7) << 4);
    const int r = p >> 7;
    const int kb = l & 127;
    const int av = ((r >> 6) * 128 + (r & 63)) * lda + (kb >> 1);
    const int bv = ((r >> 5) * 64 + (r & 31)) * ldb + (kb >> 1);
    if (i == 0) { aoff0 = av; boff0 = bv; } else { aoff1 = av; boff1 = bv; }
  }

  int arb[2], brb[2];
  #pragma unroll
  for (int ks = 0; ks < 2; ++ks) {
    arb[ks] = ((((wm * 64 + l15) * 64 + l4 * 8) * 2) + ks * 64) ^ lx;
    brb[ks] = ((((wn * 32 + l15) * 64 + l4 * 8) * 2) + ks * 64) ^ lx;
  }

  f32x4 acc[8][4] = {};
  bf16x8 a0[4][2], a1[4][2], b0[2][2], b1[2][2];

  STAGE_B(0, 0, 0); STAGE_A(0, 0, 0); STAGE_A(0, 1, 0); STAGE_B(0, 1, 0);
  STAGE_B(1, 0, 1); STAGE_A(1, 0, 1);
  asm volatile("s_waitcnt vmcnt(4)" ::: "memory");
  __builtin_amdgcn_s_barrier();

  for (int it = 0; it < niter; ++it) {
    const int tt = it * 2;
    DSREAD_A(a0, 0, 0); DSREAD_BS(b0, 0, 0);
    STAGE_A(1, 1, tt + 1);
    BARRIER_MFMA(a0, b0, 0, 0);
    DSREAD_A(a1, 0, 1);
    STAGE_B(1, 1, tt + 1);
    BARRIER_MFMA(a1, b0, 1, 0);
    DSREAD_BS(b1, 0, 1);
    STAGE_B(0, 0, tt + 2);
    BARRIER_MFMA(a0, b1, 0, 1);
    STAGE_A(0, 0, tt + 2);
    asm volatile("s_waitcnt vmcnt(4)" ::: "memory");
    BARRIER_MFMA(a1, b1, 1, 1);
    DSREAD_A(a0, 1, 0); DSREAD_BS(b0, 1, 0);
    STAGE_A(0, 1, tt + 2);
    BARRIER_MFMA(a0, b0, 0, 0);
    DSREAD_A(a1, 1, 1);
    STAGE_B(0, 1, tt + 2);
    BARRIER_MFMA(a1, b0, 1, 0);
    DSREAD_BS(b1, 1, 1);
    STAGE_B(1, 0, tt + 3);
    BARRIER_MFMA(a0, b1, 0, 1);
    STAGE_A(1, 0, tt + 3);
    asm volatile("s_waitcnt vmcnt(4)" ::: "memory");
    BARRIER_MFMA(a1, b1, 1, 1);
  }

  const int cr = l4 * 4;
  __bf16* C = (__bf16*)Cout + (size_t)bz * strideC;
  #pragma unroll
  for (int m = 0; m < 8; ++m) {
    #pragma unroll
    for (int n = 0; n < 4; ++n) {
      const long row = brow + wm * 128 + m * 16 + cr;
      const long col = bcol + wn * 64 + n * 16 + l15;
      #pragma unroll
      for (int e = 0; e < 4; ++e)
        C[(row + e) * (size_t)ldc + col] = (__bf16)__expf(acc[m][n][e] * scale);
    }
  }
}

extern "C" void kernel_launch(void* const* d_in, const int* in_sizes, int n_in,
                              void* d_out, int out_size, void* d_ws, size_t ws_size,
                              hipStream_t stream)
{
  const float* query = (const float*)d_in[0];
  const float* key   = (const float*)d_in[1];
  const float* value = (const float*)d_in[2];
  const float* wq = (const float*)d_in[3];
  const float* bq = (const float*)d_in[4];
  const float* wk = (const float*)d_in[5];
  const float* bk = (const float*)d_in[6];
  const float* wv = (const float*)d_in[7];
  const float* bv = (const float*)d_in[8];

  char* ws = (char*)d_ws;
  __bf16* Xbf     = (__bf16*)(ws + 0);           // 50,331,648 B
  __bf16* Wt      = (__bf16*)(ws + 50331648);    //  6,291,456 B
  float*  biasbuf = (float*)(ws + 56623104);     //     12,288 B
  __bf16* Qb      = (__bf16*)(ws + 56635392);    // 16,777,216 B
  __bf16* Kb      = (__bf16*)(ws + 73412608);    // 16,777,216 B
  __bf16* Vt      = (__bf16*)(ws + 90189824);    // 16,777,216 B (end 106,967,040)
  __bf16* P       = Xbf;   // alias: X dead after projections

  hipFuncSetAttribute((const void*)gemm3_kernel,  hipFuncAttributeMaxDynamicSharedMemorySize, 65536);
  hipFuncSetAttribute((const void*)gemm2b_kernel, hipFuncAttributeMaxDynamicSharedMemorySize, 65536);
  hipFuncSetAttribute((const void*)gemm8p_kernel, hipFuncAttributeMaxDynamicSharedMemorySize, 131072);

  dim3 b256(256), b512(512);

  // 1. inputs -> bf16
  cvt_in_kernel<<<dim3(8192, 1, 3), b256, 0, stream>>>(query, key, value, Xbf);
  // 2. weights transpose+convert, biases
  prep_w_kernel<<<dim3(32, 32, 3), b256, 0, stream>>>(wq, wk, wv, bq, bk, bv, Wt, biasbuf);
  // 3. projections: 256x256 tiles BK=32, grid 4x32x3 = 384 all-resident @ 2/CU
  gemm3_kernel<<<dim3(4, 32, 3), b512, 65536, stream>>>(
      Xbf, Wt, biasbuf, Qb, Kb, Vt);
  // 4. scores: P[b] = exp(Q[b] @ K[b]^T / 32) -> bf16 (unnormalized), 256 blocks
  gemm8p_kernel<<<dim3(8, 8, 4), b512, 131072, stream>>>(
      Qb, Kb, 0.03125f, P,
      1024, 1024, 1024, 2048,
      2097152L, 2097152L, 4194304L);
  // 5. PV: 128x128 tiles, grid 8x16x4 = 512 = 2.0 rounds @ 2 blocks/CU
  gemm2b_kernel<<<dim3(8, 16, 4), b256, 65536, stream>>>(
      P, Vt, (float*)d_out,
      2048, 2048, 2048, 1024,
      4194304L, 2097152L, 2097152L);

  (void)in_sizes; (void)n_in; (void)out_size; (void)ws_size;
}

// Round 12
// 170.017 us; speedup vs baseline: 1.0675x; 1.0675x over previous
//
#include <hip/hip_runtime.h>
#include <hip/hip_bf16.h>

typedef __attribute__((ext_vector_type(4))) float   f32x4;
typedef __attribute__((ext_vector_type(8))) __bf16  bf16x8;
typedef __attribute__((ext_vector_type(4))) __bf16  bf16x4;

#define NB 4
#define SS 2048
#define DD 1024

__device__ __forceinline__ void gload_lds16(const void* g, void* l) {
  __builtin_amdgcn_global_load_lds((const __attribute__((address_space(1))) void*)g,
                                   (__attribute__((address_space(3))) void*)l,
                                   16, 0, 0);
}

// merged prep: x<8192 -> fp32->bf16 convert of input z; x>=8192 -> W[z] transpose tile.
// grid (9216, 1, 3) x 256
__global__ __launch_bounds__(256) void prep_kernel(
    const float* __restrict__ q, const float* __restrict__ k, const float* __restrict__ v,
    const float* __restrict__ wq, const float* __restrict__ wk, const float* __restrict__ wv,
    const float* __restrict__ bq, const float* __restrict__ bk, const float* __restrict__ bv,
    __bf16* __restrict__ X, __bf16* __restrict__ Wt, float* __restrict__ biasbuf)
{
  const int z = blockIdx.z;
  __shared__ float t[32][33];
  if (blockIdx.x < 8192) {
    const float* src = z == 0 ? q : (z == 1 ? k : v);
    __bf16* dst = X + (size_t)z * (size_t)(NB * SS * DD);
    size_t i = ((size_t)blockIdx.x * 256 + threadIdx.x) * 4;
    float4 f = *(const float4*)&src[i];
    bf16x4 o = { (__bf16)f.x, (__bf16)f.y, (__bf16)f.z, (__bf16)f.w };
    *(bf16x4*)&dst[i] = o;
  } else {
    const int idx = blockIdx.x - 8192;          // 0..1023
    const float* W  = z == 0 ? wq : (z == 1 ? wk : wv);
    const float* bi = z == 0 ? bq : (z == 1 ? bk : bv);
    __bf16* dst = Wt + (size_t)z * (size_t)(DD * DD);
    const int n0 = (idx & 31) * 32, k0 = (idx >> 5) * 32;
    const int tx = threadIdx.x & 31, ty = threadIdx.x >> 5;
    #pragma unroll
    for (int i = 0; i < 4; i++)
      t[ty + 8 * i][tx] = W[(size_t)(k0 + ty + 8 * i) * DD + n0 + tx];
    __syncthreads();
    #pragma unroll
    for (int i = 0; i < 4; i++)
      dst[(size_t)(n0 + ty + 8 * i) * DD + k0 + tx] = (__bf16)t[tx][ty + 8 * i];
    if (idx == 0) {
      #pragma unroll
      for (int i = 0; i < 4; i++)
        biasbuf[z * DD + threadIdx.x + 256 * i] = bi[threadIdx.x + 256 * i];
    }
  }
}

// ---------------------------------------------------------------------------
// gemm2b (projections): 128x128 tile, BK=64, 4 waves, dbuf 64 KiB -> 2 blocks/CU.
// Proven R9: proj 64us, MfmaUtil 34%, conflicts 0. z==2 writes Vt[b][d][s].
// ---------------------------------------------------------------------------

#define G2A(BUF) ((BUF) * 16384)
#define G2B(BUF) (32768 + (BUF) * 16384)

#define G2_STAGE(BUF, T) do { int t_ = (T); if (t_ >= NT) t_ = 0;               \
  const __bf16* gA_ = Ablk + (size_t)t_ * 64;                                   \
  const __bf16* gB_ = Bblk + (size_t)t_ * 64;                                   \
  gload_lds16(gA_ + o0, smem + G2A(BUF) + tid * 16);                            \
  gload_lds16(gA_ + o1, smem + G2A(BUF) + 4096 + tid * 16);                     \
  gload_lds16(gA_ + o2, smem + G2A(BUF) + 8192 + tid * 16);                     \
  gload_lds16(gA_ + o3, smem + G2A(BUF) + 12288 + tid * 16);                    \
  gload_lds16(gB_ + o0, smem + G2B(BUF) + tid * 16);                            \
  gload_lds16(gB_ + o1, smem + G2B(BUF) + 4096 + tid * 16);                     \
  gload_lds16(gB_ + o2, smem + G2B(BUF) + 8192 + tid * 16);                     \
  gload_lds16(gB_ + o3, smem + G2B(BUF) + 12288 + tid * 16); } while (0)

__global__ __launch_bounds__(256, 2) void gemm2b_kernel(
    const __bf16* __restrict__ A, const __bf16* __restrict__ B,
    const float* __restrict__ bias,
    __bf16* __restrict__ Qo, __bf16* __restrict__ Ko, __bf16* __restrict__ Vt,
    int K, int lda, int ldb,
    long strideA, long strideB)
{
  extern __shared__ char smem[];

  const int gx = gridDim.x, gy = gridDim.y;
  const int nwg = gx * gy * gridDim.z;
  int lin = blockIdx.x + gx * (blockIdx.y + gy * blockIdx.z);
  const int cpx = nwg >> 3;
  int swz = (lin & 7) * cpx + (lin >> 3);
  const int bx = swz % gx;
  int rem = swz / gx;
  const int by = rem % gy;
  const int bz = rem / gy;

  const long brow = (long)by * 128, bcol = (long)bx * 128;
  const __bf16* Ablk = A + (size_t)bz * strideA + (size_t)brow * lda;
  const __bf16* Bblk = B + (size_t)bz * strideB + (size_t)bcol * ldb;

  const int tid  = threadIdx.x;
  const int lane = tid & 63;
  const int wid  = tid >> 6;
  const int wm = wid >> 1, wn = wid & 1;
  const int l15 = lane & 15, l4 = lane >> 4;
  const int lx = (lane & 7) << 4;

  const int NT = K >> 6;

  int o0, o1, o2, o3;
  #pragma unroll
  for (int i = 0; i < 4; ++i) {
    const int p = i * 4096 + tid * 16;
    const int r = p >> 7;
    const int kb = (p ^ ((r & 7) << 4)) & 127;
    const int off = r * lda + (kb >> 1);
    if (i == 0) o0 = off; else if (i == 1) o1 = off;
    else if (i == 2) o2 = off; else o3 = off;
  }

  int ara[2], brb[2];
  #pragma unroll
  for (int ks = 0; ks < 2; ++ks) {
    ara[ks] = ((((wm * 64 + l15) * 64 + l4 * 8) * 2) + ks * 64) ^ lx;
    brb[ks] = ((((wn * 64 + l15) * 64 + l4 * 8) * 2) + ks * 64) ^ lx;
  }

  f32x4 acc[4][4] = {};
  bf16x8 af[4][2], bf[4][2];

  G2_STAGE(0, 0);
  G2_STAGE(1, 1);
  asm volatile("s_waitcnt vmcnt(8)" ::: "memory");
  __builtin_amdgcn_s_barrier();

  for (int t = 0; t < NT; ++t) {
    const int cur = t & 1;
    const int abase = cur * 16384;
    const int bbase = 32768 + cur * 16384;
    #pragma unroll
    for (int mi = 0; mi < 4; ++mi)
      #pragma unroll
      for (int ks = 0; ks < 2; ++ks)
        af[mi][ks] = *(const bf16x8*)(smem + abase + ara[ks] + mi * 2048);
    #pragma unroll
    for (int ni = 0; ni < 4; ++ni)
      #pragma unroll
      for (int ks = 0; ks < 2; ++ks)
        bf[ni][ks] = *(const bf16x8*)(smem + bbase + brb[ks] + ni * 2048);
    asm volatile("s_waitcnt lgkmcnt(0)" ::: "memory");
    __builtin_amdgcn_sched_barrier(0);
    __builtin_amdgcn_s_barrier();
    G2_STAGE(cur, t + 2);
    __builtin_amdgcn_s_setprio(1);
    #pragma unroll
    for (int mi = 0; mi < 4; ++mi)
      #pragma unroll
      for (int ni = 0; ni < 4; ++ni)
        #pragma unroll
        for (int ks = 0; ks < 2; ++ks)
          acc[mi][ni] = __builtin_amdgcn_mfma_f32_16x16x32_bf16(
              af[mi][ks], bf[ni][ks], acc[mi][ni], 0, 0, 0);
    __builtin_amdgcn_s_setprio(0);
    __builtin_amdgcn_sched_barrier(0);
    asm volatile("s_waitcnt vmcnt(8)" ::: "memory");
    __builtin_amdgcn_s_barrier();
  }

  if (bz == 2) {
    #pragma unroll
    for (int mi = 0; mi < 4; ++mi) {
      #pragma unroll
      for (int ni = 0; ni < 4; ++ni) {
        const long row = brow + wm * 64 + mi * 16 + l4 * 4;
        const long col = bcol + wn * 64 + ni * 16 + l15;
        const float bvv = bias[2 * DD + col];
        const long bb = row >> 11, s = row & 2047;
        bf16x4 pk = { (__bf16)(acc[mi][ni][0] + bvv), (__bf16)(acc[mi][ni][1] + bvv),
                      (__bf16)(acc[mi][ni][2] + bvv), (__bf16)(acc[mi][ni][3] + bvv) };
        *(bf16x4*)&Vt[bb * 2097152 + col * 2048 + s] = pk;
      }
    }
  } else {
    __bf16* C = bz == 0 ? Qo : Ko;
    #pragma unroll
    for (int mi = 0; mi < 4; ++mi) {
      #pragma unroll
      for (int ni = 0; ni < 4; ++ni) {
        const long row = brow + wm * 64 + mi * 16 + l4 * 4;
        const long col = bcol + wn * 64 + ni * 16 + l15;
        const float bvv = bias[bz * DD + col];
        #pragma unroll
        for (int e = 0; e < 4; ++e)
          C[(row + e) * 1024 + col] = (__bf16)(acc[mi][ni][e] + bvv);
      }
    }
  }
}

// ---------------------------------------------------------------------------
// 256x256 8-phase counted-vmcnt GEMM (scores): P = exp(Q @ K^T * scale) -> bf16
// (unchanged, proven since R2)
// ---------------------------------------------------------------------------

#define A_OFF(BUF, MH) (((BUF)*2 + (MH)) * 16384)
#define B_OFF(BUF, NH) (65536 + ((BUF)*2 + (NH)) * 16384)

#define STAGE_A(BUF, MH, T) do { int t_ = (T); if (t_ >= NT) t_ = 0;            \
  const __bf16* gs_ = Ablk + (size_t)(MH) * (64 * (size_t)lda) + (size_t)t_ * 64; \
  gload_lds16(gs_ + aoff0, smem + A_OFF(BUF, MH) + tid * 16);                    \
  gload_lds16(gs_ + aoff1, smem + A_OFF(BUF, MH) + 8192 + tid * 16); } while (0)

#define STAGE_B(BUF, NH, T) do { int t_ = (T); if (t_ >= NT) t_ = 0;            \
  const __bf16* gs_ = Bblk + (size_t)(NH) * (32 * (size_t)ldb) + (size_t)t_ * 64; \
  gload_lds16(gs_ + boff0, smem + B_OFF(BUF, NH) + tid * 16);                    \
  gload_lds16(gs_ + boff1, smem + B_OFF(BUF, NH) + 8192 + tid * 16); } while (0)

#define DSREAD_A(DST, BUF, MH)                                                  \
  _Pragma("unroll") for (int mi = 0; mi < 4; ++mi) {                            \
    _Pragma("unroll") for (int ks = 0; ks < 2; ++ks)                            \
      DST[mi][ks] = *(const bf16x8*)(smem + A_OFF(BUF, MH) + arb[ks] + mi * 2048); }

#define DSREAD_BS(DST, BUF, NH)                                                 \
  _Pragma("unroll") for (int ni = 0; ni < 2; ++ni) {                            \
    _Pragma("unroll") for (int ks = 0; ks < 2; ++ks)                            \
      DST[ni][ks] = *(const bf16x8*)(smem + B_OFF(BUF, NH) + brb[ks] + ni * 2048); }

#define BARRIER_MFMA(AF, BF, MH, NH) do {                                       \
  __builtin_amdgcn_s_barrier();                                                 \
  asm volatile("s_waitcnt lgkmcnt(0)" ::: "memory");                            \
  __builtin_amdgcn_sched_barrier(0);                                            \
  __builtin_amdgcn_s_setprio(1);                                                \
  _Pragma("unroll") for (int mi = 0; mi < 4; ++mi)                              \
  _Pragma("unroll") for (int ni = 0; ni < 2; ++ni)                              \
  _Pragma("unroll") for (int ks = 0; ks < 2; ++ks)                              \
    acc[(MH)*4+mi][(NH)*2+ni] = __builtin_amdgcn_mfma_f32_16x16x32_bf16(        \
        AF[mi][ks], BF[ni][ks], acc[(MH)*4+mi][(NH)*2+ni], 0, 0, 0);            \
  __builtin_amdgcn_s_setprio(0);                                                \
  __builtin_amdgcn_sched_barrier(0);                                            \
  __builtin_amdgcn_s_barrier(); } while (0)

__global__ __launch_bounds__(512) void gemm8p_kernel(
    const __bf16* __restrict__ A, const __bf16* __restrict__ B,
    float scale, void* __restrict__ Cout,
    int K, int lda, int ldb, int ldc,
    long strideA, long strideB, long strideC)
{
  extern __shared__ char smem[];

  const int gx = gridDim.x, gy = gridDim.y;
  const int nwg = gx * gy * gridDim.z;
  int lin = blockIdx.x + gx * (blockIdx.y + gy * blockIdx.z);
  const int cpx = nwg >> 3;
  int swz = (lin & 7) * cpx + (lin >> 3);
  const int bx = swz % gx;
  int rem = swz / gx;
  const int by = rem % gy;
  const int bz = rem / gy;

  const long brow = (long)by * 256, bcol = (long)bx * 256;
  const __bf16* Ablk = A + (size_t)bz * strideA + (size_t)brow * lda;
  const __bf16* Bblk = B + (size_t)bz * strideB + (size_t)bcol * ldb;

  const int tid  = threadIdx.x;
  const int lane = tid & 63;
  const int wid  = tid >> 6;
  const int wm = wid >> 2, wn = wid & 3;
  const int l15 = lane & 15, l4 = lane >> 4;
  const int lx = (lane & 7) << 4;

  const int NT = K >> 6;
  const int niter = NT >> 1;

  int aoff0, aoff1, boff0, boff1;
  #pragma unroll
  for (int i = 0; i < 2; ++i) {
    const int p = i * 8192 + tid * 16;
    const int l = p ^ (((p >> 7) & 7) << 4);
    const int r = p >> 7;
    const int kb = l & 127;
    const int av = ((r >> 6) * 128 + (r & 63)) * lda + (kb >> 1);
    const int bv = ((r >> 5) * 64 + (r & 31)) * ldb + (kb >> 1);
    if (i == 0) { aoff0 = av; boff0 = bv; } else { aoff1 = av; boff1 = bv; }
  }

  int arb[2], brb[2];
  #pragma unroll
  for (int ks = 0; ks < 2; ++ks) {
    arb[ks] = ((((wm * 64 + l15) * 64 + l4 * 8) * 2) + ks * 64) ^ lx;
    brb[ks] = ((((wn * 32 + l15) * 64 + l4 * 8) * 2) + ks * 64) ^ lx;
  }

  f32x4 acc[8][4] = {};
  bf16x8 a0[4][2], a1[4][2], b0[2][2], b1[2][2];

  STAGE_B(0, 0, 0); STAGE_A(0, 0, 0); STAGE_A(0, 1, 0); STAGE_B(0, 1, 0);
  STAGE_B(1, 0, 1); STAGE_A(1, 0, 1);
  asm volatile("s_waitcnt vmcnt(4)" ::: "memory");
  __builtin_amdgcn_s_barrier();

  for (int it = 0; it < niter; ++it) {
    const int tt = it * 2;
    DSREAD_A(a0, 0, 0); DSREAD_BS(b0, 0, 0);
    STAGE_A(1, 1, tt + 1);
    BARRIER_MFMA(a0, b0, 0, 0);
    DSREAD_A(a1, 0, 1);
    STAGE_B(1, 1, tt + 1);
    BARRIER_MFMA(a1, b0, 1, 0);
    DSREAD_BS(b1, 0, 1);
    STAGE_B(0, 0, tt + 2);
    BARRIER_MFMA(a0, b1, 0, 1);
    STAGE_A(0, 0, tt + 2);
    asm volatile("s_waitcnt vmcnt(4)" ::: "memory");
    BARRIER_MFMA(a1, b1, 1, 1);
    DSREAD_A(a0, 1, 0); DSREAD_BS(b0, 1, 0);
    STAGE_A(0, 1, tt + 2);
    BARRIER_MFMA(a0, b0, 0, 0);
    DSREAD_A(a1, 1, 1);
    STAGE_B(0, 1, tt + 2);
    BARRIER_MFMA(a1, b0, 1, 0);
    DSREAD_BS(b1, 1, 1);
    STAGE_B(1, 0, tt + 3);
    BARRIER_MFMA(a0, b1, 0, 1);
    STAGE_A(1, 0, tt + 3);
    asm volatile("s_waitcnt vmcnt(4)" ::: "memory");
    BARRIER_MFMA(a1, b1, 1, 1);
  }

  const int cr = l4 * 4;
  __bf16* C = (__bf16*)Cout + (size_t)bz * strideC;
  #pragma unroll
  for (int m = 0; m < 8; ++m) {
    #pragma unroll
    for (int n = 0; n < 4; ++n) {
      const long row = brow + wm * 128 + m * 16 + cr;
      const long col = bcol + wn * 64 + n * 16 + l15;
      #pragma unroll
      for (int e = 0; e < 4; ++e)
        C[(row + e) * (size_t)ldc + col] = (__bf16)__expf(acc[m][n][e] * scale);
    }
  }
}

// ---------------------------------------------------------------------------
// gemm128 (PV): 128x256 4-phase counted-vmcnt, 96 KiB LDS, grid 256.
// out = (P @ Vt^T) / rowsum(P) -> fp32. (proven R7/R8; lower L3 traffic)
// ---------------------------------------------------------------------------

#define PV_A_OFF(BUF)     ((BUF) * 16384)
#define PV_B_OFF(BUF, NH) (32768 + ((BUF)*2 + (NH)) * 16384)

#define PV_DSA(BUF)                                                             \
  _Pragma("unroll") for (int mi = 0; mi < 4; ++mi) {                            \
    _Pragma("unroll") for (int ks = 0; ks < 2; ++ks)                            \
      af[mi][ks] = *(const bf16x8*)(smem + PV_A_OFF(BUF) + ara[ks] + mi * 2048); }

#define PV_DSB(DST, BUF, NH)                                                    \
  _Pragma("unroll") for (int ni = 0; ni < 2; ++ni) {                            \
    _Pragma("unroll") for (int ks = 0; ks < 2; ++ks)                            \
      DST[ni][ks] = *(const bf16x8*)(smem + PV_B_OFF(BUF, NH) + brb2[ks] + ni * 2048); }

#define PV_SA(BUF, T) do { int t_ = (T); if (t_ >= NT) t_ = 0;                  \
  const __bf16* gA_ = Ablk + (size_t)t_ * 64;                                   \
  gload_lds16(gA_ + aoff0, smem + PV_A_OFF(BUF) + tid * 16);                    \
  gload_lds16(gA_ + aoff1, smem + PV_A_OFF(BUF) + 8192 + tid * 16);             \
  const __bf16* gB_ = Bblk + (size_t)t_ * 64;                                   \
  gload_lds16(gB_ + boff0, smem + PV_B_OFF(BUF, 0) + tid * 16);                 \
  gload_lds16(gB_ + boff1, smem + PV_B_OFF(BUF, 0) + 8192 + tid * 16); } while (0)

#define PV_SB(BUF, T) do { int t_ = (T); if (t_ >= NT) t_ = 0;                  \
  const __bf16* gB_ = Bblk + (size_t)(128 * (size_t)ldb) + (size_t)t_ * 64;     \
  gload_lds16(gB_ + boff0, smem + PV_B_OFF(BUF, 1) + tid * 16);                 \
  gload_lds16(gB_ + boff1, smem + PV_B_OFF(BUF, 1) + 8192 + tid * 16); } while (0)

#define PV_MFMA(BF, NH, DOSUM) do {                                             \
  __builtin_amdgcn_s_barrier();                                                 \
  asm volatile("s_waitcnt lgkmcnt(0)" ::: "memory");                            \
  __builtin_amdgcn_sched_barrier(0);                                            \
  __builtin_amdgcn_s_setprio(1);                                                \
  _Pragma("unroll") for (int mi = 0; mi < 4; ++mi)                              \
  _Pragma("unroll") for (int ni = 0; ni < 2; ++ni)                              \
  _Pragma("unroll") for (int ks = 0; ks < 2; ++ks)                              \
    acc[mi][(NH)*2+ni] = __builtin_amdgcn_mfma_f32_16x16x32_bf16(               \
        af[mi][ks], BF[ni][ks], acc[mi][(NH)*2+ni], 0, 0, 0);                   \
  if (DOSUM) {                                                                  \
    _Pragma("unroll") for (int mi = 0; mi < 4; ++mi)                            \
    _Pragma("unroll") for (int ks = 0; ks < 2; ++ks)                            \
      accs[mi] = __builtin_amdgcn_mfma_f32_16x16x32_bf16(                       \
          af[mi][ks], onesf, accs[mi], 0, 0, 0); }                              \
  __builtin_amdgcn_s_setprio(0);                                                \
  __builtin_amdgcn_sched_barrier(0);                                            \
  __builtin_amdgcn_s_barrier(); } while (0)

__global__ __launch_bounds__(512) void gemm128_kernel(
    const __bf16* __restrict__ A, const __bf16* __restrict__ B,
    void* __restrict__ Cout,
    int K, int lda, int ldb, int ldc,
    long strideA, long strideB, long strideC)
{
  extern __shared__ char smem[];

  const int gx = gridDim.x, gy = gridDim.y;
  const int nwg = gx * gy * gridDim.z;
  int lin = blockIdx.x + gx * (blockIdx.y + gy * blockIdx.z);
  const int cpx = nwg >> 3;
  int swz = (lin & 7) * cpx + (lin >> 3);
  const int bx = swz % gx;
  int rem = swz / gx;
  const int by = rem % gy;
  const int bz = rem / gy;

  const long brow = (long)by * 128, bcol = (long)bx * 256;
  const __bf16* Ablk = A + (size_t)bz * strideA + (size_t)brow * lda;
  const __bf16* Bblk = B + (size_t)bz * strideB + (size_t)bcol * ldb;

  const int tid  = threadIdx.x;
  const int lane = tid & 63;
  const int wid  = tid >> 6;
  const int wm = wid >> 2, wn = wid & 3;
  const int l15 = lane & 15, l4 = lane >> 4;
  const int lx = (lane & 7) << 4;

  const int NT = K >> 6;
  const int niter = NT >> 1;

  int aoff0, aoff1, boff0, boff1;
  #pragma unroll
  for (int i = 0; i < 2; ++i) {
    const int p = i * 8192 + tid * 16;
    const int r = p >> 7;
    const int kb = (p ^ ((r & 7) << 4)) & 127;
    const int av = r * lda + (kb >> 1);
    const int bv = r * ldb + (kb >> 1);
    if (i == 0) { aoff0 = av; boff0 = bv; } else { aoff1 = av; boff1 = bv; }
  }

  int ara[2], brb2[2];
  #pragma unroll
  for (int ks = 0; ks < 2; ++ks) {
    ara[ks]  = ((((wm * 64 + l15) * 64 + l4 * 8) * 2) + ks * 64) ^ lx;
    brb2[ks] = ((((wn * 32 + l15) * 64 + l4 * 8) * 2) + ks * 64) ^ lx;
  }

  f32x4 acc[4][4] = {};
  f32x4 accs[4] = {};
  bf16x8 af[4][2], b0[2][2], b1[2][2];
  bf16x8 onesf;
  #pragma unroll
  for (int j = 0; j < 8; ++j) onesf[j] = (__bf16)1.0f;

  PV_SA(0, 0); PV_SB(0, 0); PV_SA(1, 1);
  asm volatile("s_waitcnt vmcnt(6)" ::: "memory");
  __builtin_amdgcn_s_barrier();

  for (int it = 0; it < niter; ++it) {
    const int tt = it * 2;
    PV_SB(1, tt + 1);
    asm volatile("s_waitcnt vmcnt(6)" ::: "memory");
    PV_DSA(0); PV_DSB(b0, 0, 0);
    PV_MFMA(b0, 0, 1);
    PV_SA(0, tt + 2);
    asm volatile("s_waitcnt vmcnt(6)" ::: "memory");
    PV_DSB(b1, 0, 1);
    PV_MFMA(b1, 1, 0);
    PV_SB(0, tt + 2);
    asm volatile("s_waitcnt vmcnt(6)" ::: "memory");
    PV_DSA(1); PV_DSB(b0, 1, 0);
    PV_MFMA(b0, 0, 1);
    PV_SA(1, tt + 3);
    asm volatile("s_waitcnt vmcnt(6)" ::: "memory");
    PV_DSB(b1, 1, 1);
    PV_MFMA(b1, 1, 0);
  }

  float* C = (float*)Cout + (size_t)bz * strideC;
  #pragma unroll
  for (int mi = 0; mi < 4; ++mi) {
    f32x4 inv;
    #pragma unroll
    for (int e = 0; e < 4; ++e) inv[e] = 1.0f / accs[mi][e];
    #pragma unroll
    for (int n = 0; n < 4; ++n) {
      const long row = brow + wm * 64 + mi * 16 + l4 * 4;
      const long col = bcol + (n >> 1) * 128 + wn * 32 + (n & 1) * 16 + l15;
      #pragma unroll
      for (int e = 0; e < 4; ++e)
        C[(row + e) * (size_t)ldc + col] = acc[mi][n][e] * inv[e];
    }
  }
}

extern "C" void kernel_launch(void* const* d_in, const int* in_sizes, int n_in,
                              void* d_out, int out_size, void* d_ws, size_t ws_size,
                              hipStream_t stream)
{
  const float* query = (const float*)d_in[0];
  const float* key   = (const float*)d_in[1];
  const float* value = (const float*)d_in[2];
  const float* wq = (const float*)d_in[3];
  const float* bq = (const float*)d_in[4];
  const float* wk = (const float*)d_in[5];
  const float* bk = (const float*)d_in[6];
  const float* wv = (const float*)d_in[7];
  const float* bv = (const float*)d_in[8];

  char* ws = (char*)d_ws;
  __bf16* Xbf     = (__bf16*)(ws + 0);           // 50,331,648 B
  __bf16* Wt      = (__bf16*)(ws + 50331648);    //  6,291,456 B
  float*  biasbuf = (float*)(ws + 56623104);     //     12,288 B
  __bf16* Qb      = (__bf16*)(ws + 56635392);    // 16,777,216 B
  __bf16* Kb      = (__bf16*)(ws + 73412608);    // 16,777,216 B
  __bf16* Vt      = (__bf16*)(ws + 90189824);    // 16,777,216 B (end 106,967,040)
  __bf16* P       = Xbf;   // alias: X dead after projections

  hipFuncSetAttribute((const void*)gemm2b_kernel,  hipFuncAttributeMaxDynamicSharedMemorySize, 65536);
  hipFuncSetAttribute((const void*)gemm8p_kernel,  hipFuncAttributeMaxDynamicSharedMemorySize, 131072);
  hipFuncSetAttribute((const void*)gemm128_kernel, hipFuncAttributeMaxDynamicSharedMemorySize, 131072);

  dim3 b256(256), b512(512);

  // 1. merged: inputs -> bf16 + weight transpose + bias copy
  prep_kernel<<<dim3(9216, 1, 3), b256, 0, stream>>>(
      query, key, value, wq, wk, wv, bq, bk, bv, Xbf, Wt, biasbuf);
  // 2. projections: 128x128 tiles, grid 8x64x3 = 1536 = 3 rounds @ 2/CU (R9 proven)
  gemm2b_kernel<<<dim3(8, 64, 3), b256, 65536, stream>>>(
      Xbf, Wt, biasbuf, Qb, Kb, Vt,
      1024, 1024, 1024, 8388608L, 1048576L);
  // 3. scores: P[b] = exp(Q[b] @ K[b]^T / 32) -> bf16 (unnormalized), 256 blocks
  gemm8p_kernel<<<dim3(8, 8, 4), b512, 131072, stream>>>(
      Qb, Kb, 0.03125f, P,
      1024, 1024, 1024, 2048,
      2097152L, 2097152L, 4194304L);
  // 4. PV: 128x256 tiles 4-phase, grid 4x16x4 = 256 blocks (R8 proven, lower L3 traffic)
  gemm128_kernel<<<dim3(4, 16, 4), b512, 98304, stream>>>(
      P, Vt, d_out,
      2048, 2048, 2048, 1024,
      4194304L, 2097152L, 2097152L);

  (void)in_sizes; (void)n_in; (void)out_size; (void)ws_size;
}

// Round 13
// 166.574 us; speedup vs baseline: 1.0896x; 1.0207x over previous
//
#include <hip/hip_runtime.h>
#include <hip/hip_bf16.h>

typedef __attribute__((ext_vector_type(4))) float   f32x4;
typedef __attribute__((ext_vector_type(8))) __bf16  bf16x8;
typedef __attribute__((ext_vector_type(4))) __bf16  bf16x4;

#define NB 4
#define SS 2048
#define DD 1024

__device__ __forceinline__ void gload_lds16(const void* g, void* l) {
  __builtin_amdgcn_global_load_lds((const __attribute__((address_space(1))) void*)g,
                                   (__attribute__((address_space(3))) void*)l,
                                   16, 0, 0);
}

// merged prep: x<8192 -> fp32->bf16 convert of input z; x>=8192 -> W[z] transpose tile.
// grid (9216, 1, 3) x 256
__global__ __launch_bounds__(256) void prep_kernel(
    const float* __restrict__ q, const float* __restrict__ k, const float* __restrict__ v,
    const float* __restrict__ wq, const float* __restrict__ wk, const float* __restrict__ wv,
    const float* __restrict__ bq, const float* __restrict__ bk, const float* __restrict__ bv,
    __bf16* __restrict__ X, __bf16* __restrict__ Wt, float* __restrict__ biasbuf)
{
  const int z = blockIdx.z;
  __shared__ float t[32][33];
  if (blockIdx.x < 8192) {
    const float* src = z == 0 ? q : (z == 1 ? k : v);
    __bf16* dst = X + (size_t)z * (size_t)(NB * SS * DD);
    size_t i = ((size_t)blockIdx.x * 256 + threadIdx.x) * 4;
    float4 f = *(const float4*)&src[i];
    bf16x4 o = { (__bf16)f.x, (__bf16)f.y, (__bf16)f.z, (__bf16)f.w };
    *(bf16x4*)&dst[i] = o;
  } else {
    const int idx = blockIdx.x - 8192;          // 0..1023
    const float* W  = z == 0 ? wq : (z == 1 ? wk : wv);
    const float* bi = z == 0 ? bq : (z == 1 ? bk : bv);
    __bf16* dst = Wt + (size_t)z * (size_t)(DD * DD);
    const int n0 = (idx & 31) * 32, k0 = (idx >> 5) * 32;
    const int tx = threadIdx.x & 31, ty = threadIdx.x >> 5;
    #pragma unroll
    for (int i = 0; i < 4; i++)
      t[ty + 8 * i][tx] = W[(size_t)(k0 + ty + 8 * i) * DD + n0 + tx];
    __syncthreads();
    #pragma unroll
    for (int i = 0; i < 4; i++)
      dst[(size_t)(n0 + ty + 8 * i) * DD + k0 + tx] = (__bf16)t[tx][ty + 8 * i];
    if (idx == 0) {
      #pragma unroll
      for (int i = 0; i < 4; i++)
        biasbuf[z * DD + threadIdx.x + 256 * i] = bi[threadIdx.x + 256 * i];
    }
  }
}

// ---------------------------------------------------------------------------
// gemm2b: 128x128 tile, BK=64, 4 waves, dbuf 64 KiB -> 2 blocks/CU.
// K-loop STAGGER: odd blockIdx.x starts rotated by NT/2 so the two co-resident
// blocks' MFMA/drain phases interleave instead of colliding (deterministic;
// fp32 sum reordering only).
// EPI 0: projections (bias; z==2 writes Vt[b][d][s]).  EPI 2: PV (rowsum/div).
// ---------------------------------------------------------------------------

#define G2A(BUF) ((BUF) * 16384)
#define G2B(BUF) (32768 + (BUF) * 16384)

#define G2_STAGE(BUF, T) do { int t_ = (((T) + koff) & (NT - 1));               \
  const __bf16* gA_ = Ablk + (size_t)t_ * 64;                                   \
  const __bf16* gB_ = Bblk + (size_t)t_ * 64;                                   \
  gload_lds16(gA_ + o0, smem + G2A(BUF) + tid * 16);                            \
  gload_lds16(gA_ + o1, smem + G2A(BUF) + 4096 + tid * 16);                     \
  gload_lds16(gA_ + o2, smem + G2A(BUF) + 8192 + tid * 16);                     \
  gload_lds16(gA_ + o3, smem + G2A(BUF) + 12288 + tid * 16);                    \
  gload_lds16(gB_ + o0, smem + G2B(BUF) + tid * 16);                            \
  gload_lds16(gB_ + o1, smem + G2B(BUF) + 4096 + tid * 16);                     \
  gload_lds16(gB_ + o2, smem + G2B(BUF) + 8192 + tid * 16);                     \
  gload_lds16(gB_ + o3, smem + G2B(BUF) + 12288 + tid * 16); } while (0)

template <int EPI>
__global__ __launch_bounds__(256, 2) void gemm2b_kernel(
    const __bf16* __restrict__ A, const __bf16* __restrict__ B,
    const float* __restrict__ bias, float* __restrict__ Fout,
    __bf16* __restrict__ Qo, __bf16* __restrict__ Ko, __bf16* __restrict__ Vt,
    int K, int lda, int ldb, int ldc,
    long strideA, long strideB, long strideC)
{
  extern __shared__ char smem[];

  const int gx = gridDim.x, gy = gridDim.y;
  const int nwg = gx * gy * gridDim.z;
  int lin = blockIdx.x + gx * (blockIdx.y + gy * blockIdx.z);
  const int cpx = nwg >> 3;
  int swz = (lin & 7) * cpx + (lin >> 3);
  const int bx = swz % gx;
  int rem = swz / gx;
  const int by = rem % gy;
  const int bz = rem / gy;

  const long brow = (long)by * 128, bcol = (long)bx * 128;
  const __bf16* Ablk = A + (size_t)bz * strideA + (size_t)brow * lda;
  const __bf16* Bblk = B + (size_t)bz * strideB + (size_t)bcol * ldb;

  const int tid  = threadIdx.x;
  const int lane = tid & 63;
  const int wid  = tid >> 6;
  const int wm = wid >> 1, wn = wid & 1;
  const int l15 = lane & 15, l4 = lane >> 4;
  const int lx = (lane & 7) << 4;

  const int NT = K >> 6;
  const int koff = (blockIdx.x & 1) * (NT >> 1);   // stagger co-resident pair

  int o0, o1, o2, o3;
  #pragma unroll
  for (int i = 0; i < 4; ++i) {
    const int p = i * 4096 + tid * 16;
    const int r = p >> 7;
    const int kb = (p ^ ((r & 7) << 4)) & 127;
    const int off = r * lda + (kb >> 1);
    if (i == 0) o0 = off; else if (i == 1) o1 = off;
    else if (i == 2) o2 = off; else o3 = off;
  }

  int ara[2], brb[2];
  #pragma unroll
  for (int ks = 0; ks < 2; ++ks) {
    ara[ks] = ((((wm * 64 + l15) * 64 + l4 * 8) * 2) + ks * 64) ^ lx;
    brb[ks] = ((((wn * 64 + l15) * 64 + l4 * 8) * 2) + ks * 64) ^ lx;
  }

  f32x4 acc[4][4] = {};
  f32x4 accs[4] = {};
  bf16x8 af[4][2], bf[4][2];
  bf16x8 onesf;
  #pragma unroll
  for (int j = 0; j < 8; ++j) onesf[j] = (__bf16)1.0f;

  G2_STAGE(0, 0);
  G2_STAGE(1, 1);
  asm volatile("s_waitcnt vmcnt(8)" ::: "memory");
  __builtin_amdgcn_s_barrier();

  for (int t = 0; t < NT; ++t) {
    const int cur = t & 1;
    const int abase = cur * 16384;
    const int bbase = 32768 + cur * 16384;
    #pragma unroll
    for (int mi = 0; mi < 4; ++mi)
      #pragma unroll
      for (int ks = 0; ks < 2; ++ks)
        af[mi][ks] = *(const bf16x8*)(smem + abase + ara[ks] + mi * 2048);
    #pragma unroll
    for (int ni = 0; ni < 4; ++ni)
      #pragma unroll
      for (int ks = 0; ks < 2; ++ks)
        bf[ni][ks] = *(const bf16x8*)(smem + bbase + brb[ks] + ni * 2048);
    asm volatile("s_waitcnt lgkmcnt(0)" ::: "memory");
    __builtin_amdgcn_sched_barrier(0);
    __builtin_amdgcn_s_barrier();
    G2_STAGE(cur, t + 2);
    __builtin_amdgcn_s_setprio(1);
    #pragma unroll
    for (int mi = 0; mi < 4; ++mi)
      #pragma unroll
      for (int ni = 0; ni < 4; ++ni)
        #pragma unroll
        for (int ks = 0; ks < 2; ++ks)
          acc[mi][ni] = __builtin_amdgcn_mfma_f32_16x16x32_bf16(
              af[mi][ks], bf[ni][ks], acc[mi][ni], 0, 0, 0);
    if constexpr (EPI == 2) {
      #pragma unroll
      for (int mi = 0; mi < 4; ++mi)
        #pragma unroll
        for (int ks = 0; ks < 2; ++ks)
          accs[mi] = __builtin_amdgcn_mfma_f32_16x16x32_bf16(
              af[mi][ks], onesf, accs[mi], 0, 0, 0);
    }
    __builtin_amdgcn_s_setprio(0);
    __builtin_amdgcn_sched_barrier(0);
    asm volatile("s_waitcnt vmcnt(8)" ::: "memory");
    __builtin_amdgcn_s_barrier();
  }

  if constexpr (EPI == 2) {
    float* C = Fout + (size_t)bz * strideC;
    #pragma unroll
    for (int mi = 0; mi < 4; ++mi) {
      f32x4 inv;
      #pragma unroll
      for (int e = 0; e < 4; ++e) inv[e] = 1.0f / accs[mi][e];
      #pragma unroll
      for (int ni = 0; ni < 4; ++ni) {
        const long row = brow + wm * 64 + mi * 16 + l4 * 4;
        const long col = bcol + wn * 64 + ni * 16 + l15;
        #pragma unroll
        for (int e = 0; e < 4; ++e)
          C[(row + e) * (size_t)ldc + col] = acc[mi][ni][e] * inv[e];
      }
    }
  } else {
    if (bz == 2) {
      #pragma unroll
      for (int mi = 0; mi < 4; ++mi) {
        #pragma unroll
        for (int ni = 0; ni < 4; ++ni) {
          const long row = brow + wm * 64 + mi * 16 + l4 * 4;
          const long col = bcol + wn * 64 + ni * 16 + l15;
          const float bvv = bias[2 * DD + col];
          const long bb = row >> 11, s = row & 2047;
          bf16x4 pk = { (__bf16)(acc[mi][ni][0] + bvv), (__bf16)(acc[mi][ni][1] + bvv),
                        (__bf16)(acc[mi][ni][2] + bvv), (__bf16)(acc[mi][ni][3] + bvv) };
          *(bf16x4*)&Vt[bb * 2097152 + col * 2048 + s] = pk;
        }
      }
    } else {
      __bf16* C = bz == 0 ? Qo : Ko;
      #pragma unroll
      for (int mi = 0; mi < 4; ++mi) {
        #pragma unroll
        for (int ni = 0; ni < 4; ++ni) {
          const long row = brow + wm * 64 + mi * 16 + l4 * 4;
          const long col = bcol + wn * 64 + ni * 16 + l15;
          const float bvv = bias[bz * DD + col];
          #pragma unroll
          for (int e = 0; e < 4; ++e)
            C[(row + e) * 1024 + col] = (__bf16)(acc[mi][ni][e] + bvv);
        }
      }
    }
  }
}

// ---------------------------------------------------------------------------
// 256x256 8-phase counted-vmcnt GEMM (scores): P = exp(Q @ K^T * scale) -> bf16
// (unchanged, proven since R2; 1 block/CU so no stagger)
// ---------------------------------------------------------------------------

#define A_OFF(BUF, MH) (((BUF)*2 + (MH)) * 16384)
#define B_OFF(BUF, NH) (65536 + ((BUF)*2 + (NH)) * 16384)

#define STAGE_A(BUF, MH, T) do { int t_ = (T); if (t_ >= NT) t_ = 0;            \
  const __bf16* gs_ = Ablk + (size_t)(MH) * (64 * (size_t)lda) + (size_t)t_ * 64; \
  gload_lds16(gs_ + aoff0, smem + A_OFF(BUF, MH) + tid * 16);                    \
  gload_lds16(gs_ + aoff1, smem + A_OFF(BUF, MH) + 8192 + tid * 16); } while (0)

#define STAGE_B(BUF, NH, T) do { int t_ = (T); if (t_ >= NT) t_ = 0;            \
  const __bf16* gs_ = Bblk + (size_t)(NH) * (32 * (size_t)ldb) + (size_t)t_ * 64; \
  gload_lds16(gs_ + boff0, smem + B_OFF(BUF, NH) + tid * 16);                    \
  gload_lds16(gs_ + boff1, smem + B_OFF(BUF, NH) + 8192 + tid * 16); } while (0)

#define DSREAD_A(DST, BUF, MH)                                                  \
  _Pragma("unroll") for (int mi = 0; mi < 4; ++mi) {                            \
    _Pragma("unroll") for (int ks = 0; ks < 2; ++ks)                            \
      DST[mi][ks] = *(const bf16x8*)(smem + A_OFF(BUF, MH) + arb[ks] + mi * 2048); }

#define DSREAD_BS(DST, BUF, NH)                                                 \
  _Pragma("unroll") for (int ni = 0; ni < 2; ++ni) {                            \
    _Pragma("unroll") for (int ks = 0; ks < 2; ++ks)                            \
      DST[ni][ks] = *(const bf16x8*)(smem + B_OFF(BUF, NH) + brb[ks] + ni * 2048); }

#define BARRIER_MFMA(AF, BF, MH, NH) do {                                       \
  __builtin_amdgcn_s_barrier();                                                 \
  asm volatile("s_waitcnt lgkmcnt(0)" ::: "memory");                            \
  __builtin_amdgcn_sched_barrier(0);                                            \
  __builtin_amdgcn_s_setprio(1);                                                \
  _Pragma("unroll") for (int mi = 0; mi < 4; ++mi)                              \
  _Pragma("unroll") for (int ni = 0; ni < 2; ++ni)                              \
  _Pragma("unroll") for (int ks = 0; ks < 2; ++ks)                              \
    acc[(MH)*4+mi][(NH)*2+ni] = __builtin_amdgcn_mfma_f32_16x16x32_bf16(        \
        AF[mi][ks], BF[ni][ks], acc[(MH)*4+mi][(NH)*2+ni], 0, 0, 0);            \
  __builtin_amdgcn_s_setprio(0);                                                \
  __builtin_amdgcn_sched_barrier(0);                                            \
  __builtin_amdgcn_s_barrier(); } while (0)

__global__ __launch_bounds__(512) void gemm8p_kernel(
    const __bf16* __restrict__ A, const __bf16* __restrict__ B,
    float scale, void* __restrict__ Cout,
    int K, int lda, int ldb, int ldc,
    long strideA, long strideB, long strideC)
{
  extern __shared__ char smem[];

  const int gx = gridDim.x, gy = gridDim.y;
  const int nwg = gx * gy * gridDim.z;
  int lin = blockIdx.x + gx * (blockIdx.y + gy * blockIdx.z);
  const int cpx = nwg >> 3;
  int swz = (lin & 7) * cpx + (lin >> 3);
  const int bx = swz % gx;
  int rem = swz / gx;
  const int by = rem % gy;
  const int bz = rem / gy;

  const long brow = (long)by * 256, bcol = (long)bx * 256;
  const __bf16* Ablk = A + (size_t)bz * strideA + (size_t)brow * lda;
  const __bf16* Bblk = B + (size_t)bz * strideB + (size_t)bcol * ldb;

  const int tid  = threadIdx.x;
  const int lane = tid & 63;
  const int wid  = tid >> 6;
  const int wm = wid >> 2, wn = wid & 3;
  const int l15 = lane & 15, l4 = lane >> 4;
  const int lx = (lane & 7) << 4;

  const int NT = K >> 6;
  const int niter = NT >> 1;

  int aoff0, aoff1, boff0, boff1;
  #pragma unroll
  for (int i = 0; i < 2; ++i) {
    const int p = i * 8192 + tid * 16;
    const int l = p ^ (((p >> 7) & 7) << 4);
    const int r = p >> 7;
    const int kb = l & 127;
    const int av = ((r >> 6) * 128 + (r & 63)) * lda + (kb >> 1);
    const int bv = ((r >> 5) * 64 + (r & 31)) * ldb + (kb >> 1);
    if (i == 0) { aoff0 = av; boff0 = bv; } else { aoff1 = av; boff1 = bv; }
  }

  int arb[2], brb[2];
  #pragma unroll
  for (int ks = 0; ks < 2; ++ks) {
    arb[ks] = ((((wm * 64 + l15) * 64 + l4 * 8) * 2) + ks * 64) ^ lx;
    brb[ks] = ((((wn * 32 + l15) * 64 + l4 * 8) * 2) + ks * 64) ^ lx;
  }

  f32x4 acc[8][4] = {};
  bf16x8 a0[4][2], a1[4][2], b0[2][2], b1[2][2];

  STAGE_B(0, 0, 0); STAGE_A(0, 0, 0); STAGE_A(0, 1, 0); STAGE_B(0, 1, 0);
  STAGE_B(1, 0, 1); STAGE_A(1, 0, 1);
  asm volatile("s_waitcnt vmcnt(4)" ::: "memory");
  __builtin_amdgcn_s_barrier();

  for (int it = 0; it < niter; ++it) {
    const int tt = it * 2;
    DSREAD_A(a0, 0, 0); DSREAD_BS(b0, 0, 0);
    STAGE_A(1, 1, tt + 1);
    BARRIER_MFMA(a0, b0, 0, 0);
    DSREAD_A(a1, 0, 1);
    STAGE_B(1, 1, tt + 1);
    BARRIER_MFMA(a1, b0, 1, 0);
    DSREAD_BS(b1, 0, 1);
    STAGE_B(0, 0, tt + 2);
    BARRIER_MFMA(a0, b1, 0, 1);
    STAGE_A(0, 0, tt + 2);
    asm volatile("s_waitcnt vmcnt(4)" ::: "memory");
    BARRIER_MFMA(a1, b1, 1, 1);
    DSREAD_A(a0, 1, 0); DSREAD_BS(b0, 1, 0);
    STAGE_A(0, 1, tt + 2);
    BARRIER_MFMA(a0, b0, 0, 0);
    DSREAD_A(a1, 1, 1);
    STAGE_B(0, 1, tt + 2);
    BARRIER_MFMA(a1, b0, 1, 0);
    DSREAD_BS(b1, 1, 1);
    STAGE_B(1, 0, tt + 3);
    BARRIER_MFMA(a0, b1, 0, 1);
    STAGE_A(1, 0, tt + 3);
    asm volatile("s_waitcnt vmcnt(4)" ::: "memory");
    BARRIER_MFMA(a1, b1, 1, 1);
  }

  const int cr = l4 * 4;
  __bf16* C = (__bf16*)Cout + (size_t)bz * strideC;
  #pragma unroll
  for (int m = 0; m < 8; ++m) {
    #pragma unroll
    for (int n = 0; n < 4; ++n) {
      const long row = brow + wm * 128 + m * 16 + cr;
      const long col = bcol + wn * 64 + n * 16 + l15;
      #pragma unroll
      for (int e = 0; e < 4; ++e)
        C[(row + e) * (size_t)ldc + col] = (__bf16)__expf(acc[m][n][e] * scale);
    }
  }
}

extern "C" void kernel_launch(void* const* d_in, const int* in_sizes, int n_in,
                              void* d_out, int out_size, void* d_ws, size_t ws_size,
                              hipStream_t stream)
{
  const float* query = (const float*)d_in[0];
  const float* key   = (const float*)d_in[1];
  const float* value = (const float*)d_in[2];
  const float* wq = (const float*)d_in[3];
  const float* bq = (const float*)d_in[4];
  const float* wk = (const float*)d_in[5];
  const float* bk = (const float*)d_in[6];
  const float* wv = (const float*)d_in[7];
  const float* bv = (const float*)d_in[8];

  char* ws = (char*)d_ws;
  __bf16* Xbf     = (__bf16*)(ws + 0);           // 50,331,648 B
  __bf16* Wt      = (__bf16*)(ws + 50331648);    //  6,291,456 B
  float*  biasbuf = (float*)(ws + 56623104);     //     12,288 B
  __bf16* Qb      = (__bf16*)(ws + 56635392);    // 16,777,216 B
  __bf16* Kb      = (__bf16*)(ws + 73412608);    // 16,777,216 B
  __bf16* Vt      = (__bf16*)(ws + 90189824);    // 16,777,216 B (end 106,967,040)
  __bf16* P       = Xbf;   // alias: X dead after projections

  hipFuncSetAttribute((const void*)gemm2b_kernel<0>, hipFuncAttributeMaxDynamicSharedMemorySize, 65536);
  hipFuncSetAttribute((const void*)gemm2b_kernel<2>, hipFuncAttributeMaxDynamicSharedMemorySize, 65536);
  hipFuncSetAttribute((const void*)gemm8p_kernel,    hipFuncAttributeMaxDynamicSharedMemorySize, 131072);

  dim3 b256(256), b512(512);

  // 1. merged: inputs -> bf16 + weight transpose + bias copy
  prep_kernel<<<dim3(9216, 1, 3), b256, 0, stream>>>(
      query, key, value, wq, wk, wv, bq, bk, bv, Xbf, Wt, biasbuf);
  // 2. projections: 128x128 tiles, grid 8x64x3 = 1536 = 3 rounds @ 2/CU, staggered
  gemm2b_kernel<0><<<dim3(8, 64, 3), b256, 65536, stream>>>(
      Xbf, Wt, biasbuf, nullptr, Qb, Kb, Vt,
      1024, 1024, 1024, 1024,
      8388608L, 1048576L, 0L);
  // 3. scores: P[b] = exp(Q[b] @ K[b]^T / 32) -> bf16 (unnormalized), 256 blocks
  gemm8p_kernel<<<dim3(8, 8, 4), b512, 131072, stream>>>(
      Qb, Kb, 0.03125f, P,
      1024, 1024, 1024, 2048,
      2097152L, 2097152L, 4194304L);
  // 4. PV: 128x128 tiles, grid 8x16x4 = 512 = 2 rounds @ 2/CU, staggered
  gemm2b_kernel<2><<<dim3(8, 16, 4), b256, 65536, stream>>>(
      P, Vt, nullptr, (float*)d_out, nullptr, nullptr, nullptr,
      2048, 2048, 2048, 1024,
      4194304L, 2097152L, 2097152L);

  (void)in_sizes; (void)n_in; (void)out_size; (void)ws_size;
}